// Round 26
// baseline (93.810 us; speedup 1.0000x reference)
//
#include <hip/hip_runtime.h>
#include <hip/hip_bf16.h>

#define BATCH 8
#define CTX   2048
#define EMB   1024
#define HD    128
#define VSTR  2080   // Vt row stride (elems)

using bf16x8 = __attribute__((ext_vector_type(8))) short;
using fx4    = __attribute__((ext_vector_type(4))) float;

__device__ __forceinline__ ushort f2bf(float f) {
    union { float f; unsigned u; } v; v.f = f;
    unsigned u = v.u;
    u += 0x7fffu + ((u >> 16) & 1u);   // RNE
    return (ushort)(u >> 16);
}

__device__ __forceinline__ unsigned cvtpk(float a, float b) {
    unsigned r;
    asm("v_cvt_pk_bf16_f32 %0, %1, %2" : "=v"(r) : "v"(a), "v"(b));
    return r;
}

__device__ __forceinline__ float exp2a(float x) {   // v_exp_f32 = 2^x
    float r;
    asm("v_exp_f32 %0, %1" : "=v"(r) : "v"(x));
    return r;
}

__device__ __forceinline__ void gload16(const void* g, void* l) {
    __builtin_amdgcn_global_load_lds(
        (const __attribute__((address_space(1))) unsigned*)g,
        (__attribute__((address_space(3))) unsigned*)l, 16, 0, 0);
}

// ---------------- kernel 1: W (E,H) fp32 -> Wt (3,H,E) bf16 (LDS transpose) -
__global__ __launch_bounds__(256) void wt_kernel(
        const float* __restrict__ Wq, const float* __restrict__ Wk,
        const float* __restrict__ Wv, ushort* __restrict__ Wt) {
    __shared__ ushort lds[64][65];
    const int w  = blockIdx.z;
    const int e0 = blockIdx.x * 64;
    const int h0 = blockIdx.y * 64;
    const float* W = (w == 0) ? Wq : (w == 1) ? Wk : Wv;
    const int tl = threadIdx.x & 63;
    const int tg = threadIdx.x >> 6;
#pragma unroll
    for (int rr = 0; rr < 16; ++rr) {
        const int el = rr * 4 + tg;
        lds[el][tl] = f2bf(W[(size_t)(e0 + el) * HD + h0 + tl]);
    }
    __syncthreads();
#pragma unroll
    for (int rr = 0; rr < 16; ++rr) {
        const int hl = rr * 4 + tg;
        Wt[((size_t)w * HD + h0 + hl) * EMB + e0 + tl] = lds[tl][hl];
    }
}

// ---------------- kernel 2: projection v7 (split counted vmcnt) -------------
__global__ __launch_bounds__(256) void proj_kernel(
        const float* __restrict__ x, const ushort* __restrict__ Wt,
        ushort* __restrict__ q, ushort* __restrict__ k, ushort* __restrict__ vt) {
    __shared__ __align__(16) float  As[2][32 * 64];   // 16 KB (dbuf)
    __shared__ __align__(16) ushort Bs[192 * 64];     // 24 KB (single, wave-split)

    const int t    = threadIdx.x;
    const int wave = t >> 6;
    const int lane = t & 63;
    const int lo = lane & 15, hi = lane >> 4;
    const int brow = blockIdx.x * 32;
    const int bcol = blockIdx.y * 192;
    const int kph  = (blockIdx.x ^ (blockIdx.y << 3)) & 15;   // stagger

    fx4 acc[2][3];
#pragma unroll
    for (int m2 = 0; m2 < 2; m2++)
#pragma unroll
        for (int n = 0; n < 3; n++) acc[m2][n] = fx4{0.f, 0.f, 0.f, 0.f};

    const int arow_s = t >> 4;
    const int acol_s = ((t & 15) ^ (arow_s & 7)) << 2;        // f32 elems
    const char* Bw = (const char*)Bs + wave * 6144;

#define ASTAGE(bi, k0_) do {                                                    \
    _Pragma("unroll")                                                           \
    for (int r = 0; r < 2; ++r)                                                 \
        gload16(x + (size_t)(brow + r * 16 + arow_s) * EMB + (k0_) + acol_s,    \
                (char*)As[bi] + r * 4096 + wave * 1024);                        \
} while (0)

#define BSTAGE(k0_) do {                                                        \
    _Pragma("unroll")                                                           \
    for (int r = 0; r < 6; ++r) {                                               \
        const int ci  = r * 64 + lane;                                          \
        const int rowL = ci >> 3;                                               \
        const int slot = (ci & 7) ^ (rowL & 7);                                 \
        gload16(Wt + (size_t)(bcol + wave * 48 + rowL) * EMB + (k0_) + (slot << 3), \
                (char*)Bs + wave * 6144 + r * 1024);                            \
    }                                                                           \
} while (0)

    {
        const int k0 = (kph & 15) << 6;
        ASTAGE(0, k0);
        BSTAGE(k0);
    }

    for (int i = 0; i < 16; ++i) {
        asm volatile("s_waitcnt vmcnt(6)" ::: "memory");
        __builtin_amdgcn_sched_barrier(0);
        __builtin_amdgcn_s_barrier();          // A(i) visible to all waves
        __builtin_amdgcn_sched_barrier(0);

        if (i + 1 < 16) ASTAGE((i + 1) & 1, (((i + 1 + kph) & 15) << 6));

        const char* Ab = (const char*)As[i & 1];
        bf16x8 afr[2][2];
#pragma unroll
        for (int m2 = 0; m2 < 2; m2++) {
            const int rowA = m2 * 16 + lo;
            const unsigned sw = (rowA & 7) << 4;
#pragma unroll
            for (int ks2 = 0; ks2 < 2; ks2++) {
                const unsigned ub = rowA * 256 + ks2 * 128 + hi * 32;
                fx4 a0 = *(const fx4*)(Ab + (ub ^ sw));
                fx4 a1 = *(const fx4*)(Ab + ((ub + 16) ^ sw));
                union { unsigned u[4]; bf16x8 v; } pk;
                pk.u[0] = cvtpk(a0[0], a0[1]);
                pk.u[1] = cvtpk(a0[2], a0[3]);
                pk.u[2] = cvtpk(a1[0], a1[1]);
                pk.u[3] = cvtpk(a1[2], a1[3]);
                afr[m2][ks2] = pk.v;
            }
        }
        if (i + 1 < 16) asm volatile("s_waitcnt vmcnt(2)" ::: "memory");
        else            asm volatile("s_waitcnt vmcnt(0)" ::: "memory");
        __builtin_amdgcn_sched_barrier(0);

        bf16x8 bfr[2][3];
#pragma unroll
        for (int ks2 = 0; ks2 < 2; ks2++)
#pragma unroll
            for (int n = 0; n < 3; n++) {
                const int rowL = n * 16 + lo;               // key = lo&7
                const unsigned ub = rowL * 128 + ks2 * 64 + hi * 16;
                bfr[ks2][n] = *(const bf16x8*)(Bw + (ub ^ ((lo & 7) << 4)));
            }
        asm volatile("s_waitcnt lgkmcnt(0)" ::: "memory");
        __builtin_amdgcn_sched_barrier(0);
        if (i + 1 < 16) BSTAGE((((i + 1 + kph) & 15) << 6));
        __builtin_amdgcn_sched_barrier(0);

        __builtin_amdgcn_s_setprio(1);
#pragma unroll
        for (int ks2 = 0; ks2 < 2; ks2++)
#pragma unroll
            for (int m2 = 0; m2 < 2; m2++)
#pragma unroll
                for (int n = 0; n < 3; n++)
                    acc[m2][n] = __builtin_amdgcn_mfma_f32_16x16x32_bf16(
                        afr[m2][ks2], bfr[ks2][n], acc[m2][n], 0, 0, 0);
        __builtin_amdgcn_s_setprio(0);
    }
#undef ASTAGE
#undef BSTAGE

    const float qscale = 0.045084219f;   // (1/sqrt(1024)) * log2(e)
#pragma unroll
    for (int n = 0; n < 3; n++) {
        const int col = bcol + wave * 48 + n * 16 + lo;
        const int bnn = col >> 7;
        const int cc  = col & 127;
#pragma unroll
        for (int m2 = 0; m2 < 2; m2++) {
#pragma unroll
            for (int j = 0; j < 4; j++) {
                const int r = brow + m2 * 16 + hi * 4 + j;
                if (bnn == 0)      q[(size_t)r * HD + cc] = f2bf(acc[m2][n][j] * qscale);
                else if (bnn == 1) k[(size_t)r * HD + cc] = f2bf(acc[m2][n][j]);
                else {
                    const int bb2 = r >> 11, ccc = r & (CTX - 1);
                    vt[((size_t)bb2 * HD + cc) * VSTR + ccc] = f2bf(acc[m2][n][j]);
                }
            }
        }
    }
}

// ---------------- kernel 3: attention v11 (reg-dbuf V, zero PV wait) --------
// As v10 (512 blocks x 4 waves, 2-phase serpentine, private K dbuf,
// barrier-free counted-vmcnt loop) but V is REGISTER double-buffered:
// V(it) is loaded one full iteration early, so the loop-top vmcnt(16)
// drains exactly {V(it), K(it)} (both issued last iter, FIFO) and PV
// needs NO wait. Static vfA/vfB selection via manual 2x unroll (rule #20).
__global__ __launch_bounds__(256) void attn_kernel(
        const ushort* __restrict__ q, const ushort* __restrict__ k,
        const ushort* __restrict__ vt, float* __restrict__ out) {
    __shared__ __align__(16) char Ks[2][4][8192];  // [buf][wave][32 rows x 256B]
    __shared__ __align__(16) char p_lds[4][1280];  // per-wave P [16][80B]

    const int id   = blockIdx.x;
    const int b    = id & 7;                      // one batch per XCD
    const int p    = id >> 3;                     // 0..63
    const int t    = threadIdx.x;
    const int w    = t >> 6;                      // wave = kv column quarter
    const int lane = t & 63;
    const int lo = lane & 15, hi = lane >> 4;

    const ushort* qb = q  + (size_t)b * CTX * HD;
    const ushort* kb = k  + (size_t)b * CTX * HD;
    const ushort* vb = vt + (size_t)b * HD * VSTR;

    // merge scratch (aliases Ks buf0 areas; only touched after loop + sync)
    float* oB  = (float*)&Ks[0][0][0];    // [3][16][128] f32 = 24 KB
    float* mlB = (float*)&Ks[0][3][0];    // [3][2][16] f32

#define KSTAGE(bi, kv0_) do {                                                  \
    _Pragma("unroll")                                                          \
    for (int r = 0; r < 8; ++r) {                                              \
        const int rl  = r * 4 + (lane >> 4);                                   \
        const int key = (rl >> 1) & 7;                                         \
        gload16(kb + (size_t)((kv0_) + w * 32 + rl) * HD + (((lane & 15) ^ key) << 3), \
                Ks[bi][w] + r * 1024);                                         \
    }                                                                          \
} while (0)

#define VLOAD(VD, kv0_) do {                                                   \
    _Pragma("unroll")                                                          \
    for (int h = 0; h < 8; ++h)                                                \
        VD[h] = *(const bf16x8*)(vb + (size_t)(h * 16 + lo) * VSTR + (kv0_) + w * 32 + hi * 8); \
} while (0)

// One KV iteration. VCUR was loaded one iteration ago (drained by the
// vmcnt below); VNXT is issued here. Steady-state FIFO at body top:
// {V(it) 8, K(it) 8} outstanding; issue {V(it+1) 8, K(it+1) 8} -> 32;
// vmcnt(16) drains exactly {V(it), K(it)}. Tail: nothing issued, vmcnt(0).
#define ABODY(it_, VCUR, VNXT) do {                                            \
    const int kv0_b = (it_) * 128;                                             \
    if ((it_) + 1 < nkv) {                                                     \
        VLOAD(VNXT, kv0_b + 128);                                              \
        __builtin_amdgcn_sched_barrier(0);                                     \
        KSTAGE(((it_) + 1) & 1, kv0_b + 128);                                  \
        __builtin_amdgcn_sched_barrier(0);                                     \
        asm volatile("s_waitcnt vmcnt(16)" ::: "memory");                      \
    } else {                                                                   \
        asm volatile("s_waitcnt vmcnt(0)" ::: "memory");                       \
    }                                                                          \
    __builtin_amdgcn_sched_barrier(0);                                         \
    const char* Kb_b = Ks[(it_) & 1][w];                                       \
    fx4 s0 = fx4{0.f, 0.f, 0.f, 0.f};                                          \
    fx4 s1 = fx4{0.f, 0.f, 0.f, 0.f};                                          \
    __builtin_amdgcn_s_setprio(1);                                             \
    _Pragma("unroll")                                                          \
    for (int ks = 0; ks < 4; ks++) {                                           \
        bf16x8 kf0 = *(const bf16x8*)(Kb_b + (2 * lo) * 256 +                  \
                      ((ks * 64 + hi * 16) ^ ((lo & 7) << 4)));                \
        s0 = __builtin_amdgcn_mfma_f32_16x16x32_bf16(qf[ks], kf0, s0, 0, 0, 0);\
        bf16x8 kf1 = *(const bf16x8*)(Kb_b + (2 * lo + 1) * 256 +              \
                      ((ks * 64 + hi * 16) ^ ((lo & 7) << 4)));                \
        s1 = __builtin_amdgcn_mfma_f32_16x16x32_bf16(qf[ks], kf1, s1, 0, 0, 0);\
    }                                                                          \
    __builtin_amdgcn_s_setprio(0);                                             \
    const bool diag_b = (kv0_b + 128 > q0);                                    \
    float pmax_b[4];                                                           \
    int allok_b = 1;                                                           \
    _Pragma("unroll")                                                          \
    for (int j = 0; j < 4; j++) {                                              \
        const int r = q0 + hi * 4 + j;                                         \
        if (diag_b) {                                                          \
            const int c0 = kv0_b + w * 32 + 2 * lo;                            \
            if (c0 > r)     s0[j] = -INFINITY;                                 \
            if (c0 + 1 > r) s1[j] = -INFINITY;                                 \
        }                                                                      \
        pmax_b[j] = fmaxf(s0[j], s1[j]);                                       \
        allok_b &= (pmax_b[j] <= m[j] + 23.0f);                                \
    }                                                                          \
    if (!__all(allok_b)) {                                                     \
        _Pragma("unroll")                                                      \
        for (int j = 0; j < 4; j++) {                                          \
            float mx = pmax_b[j];                                              \
            mx = fmaxf(mx, __shfl_xor(mx, 1));                                 \
            mx = fmaxf(mx, __shfl_xor(mx, 2));                                 \
            mx = fmaxf(mx, __shfl_xor(mx, 4));                                 \
            mx = fmaxf(mx, __shfl_xor(mx, 8));                                 \
            const float mn = fmaxf(m[j], mx);                                  \
            const float f  = exp2a(m[j] - mn);                                 \
            l[j] *= f;                                                         \
            _Pragma("unroll")                                                  \
            for (int h = 0; h < 8; h++) o[h][j] *= f;                          \
            m[j] = mn;                                                         \
        }                                                                      \
    }                                                                          \
    _Pragma("unroll")                                                          \
    for (int j = 0; j < 4; j++) {                                              \
        const float p0 = exp2a(s0[j] - m[j]);                                  \
        const float p1 = exp2a(s1[j] - m[j]);                                  \
        l[j] += p0 + p1;                                                       \
        *(unsigned*)(p_lds[w] + (hi * 4 + j) * 80 + lo * 4) = cvtpk(p0, p1);   \
    }                                                                          \
    asm volatile("" ::: "memory");                                             \
    bf16x8 pa_b = *(const bf16x8*)(p_lds[w] + lo * 80 + hi * 16);              \
    __builtin_amdgcn_s_setprio(1);                                             \
    _Pragma("unroll")                                                          \
    for (int h = 0; h < 8; h++)                                                \
        o[h] = __builtin_amdgcn_mfma_f32_16x16x32_bf16(pa_b, VCUR[h], o[h], 0, 0, 0); \
    __builtin_amdgcn_s_setprio(0);                                             \
} while (0)

    for (int phase = 0; phase < 2; ++phase) {
        const int qt = phase ? p : (127 - p);
        const int q0 = qt * 16;
        const int nkv = qt / 8 + 1;

        bf16x8 qf[4];
#pragma unroll
        for (int ks = 0; ks < 4; ks++)
            qf[ks] = *(const bf16x8*)(qb + (size_t)(q0 + lo) * HD + ks * 32 + hi * 8);

        fx4 o[8];
#pragma unroll
        for (int h = 0; h < 8; h++) o[h] = fx4{0.f, 0.f, 0.f, 0.f};
        float m[4], l[4];
#pragma unroll
        for (int j = 0; j < 4; j++) { m[j] = 0.f; l[j] = 0.f; }

        bf16x8 vfA[8], vfB[8];
        // prologue: V(0), K(0) -> the body-0 vmcnt(16) drains exactly these
        VLOAD(vfA, 0);
        KSTAGE(0, 0);

        for (int it2 = 0; it2 < nkv; it2 += 2) {
            ABODY(it2, vfA, vfB);
            if (it2 + 1 < nkv) ABODY(it2 + 1, vfB, vfA);
        }

        // ---- cross-lane l reduce (16-lane groups) ----
#pragma unroll
        for (int j = 0; j < 4; j++) {
            l[j] += __shfl_xor(l[j], 1);
            l[j] += __shfl_xor(l[j], 2);
            l[j] += __shfl_xor(l[j], 4);
            l[j] += __shfl_xor(l[j], 8);
        }

        // ---- merge the four kv-quarter partials ----
        __syncthreads();   // all waves done with Ks reads
        if (w > 0) {
#pragma unroll
            for (int j = 0; j < 4; j++) {
                const int row = hi * 4 + j;
                if (lo == 0) { mlB[(w - 1) * 32 + row] = m[j]; mlB[(w - 1) * 32 + 16 + row] = l[j]; }
#pragma unroll
                for (int h = 0; h < 8; h++)
                    oB[(w - 1) * 2048 + row * 128 + h * 16 + lo] = o[h][j];
            }
        }
        __syncthreads();
        if (w == 0) {
            float* ob = out + ((size_t)b * CTX + q0) * HD;
#pragma unroll
            for (int j = 0; j < 4; j++) {
                const int row = hi * 4 + j;
                float mp[3], lp[3];
                float mt = m[j];
#pragma unroll
                for (int pp = 0; pp < 3; pp++) {
                    mp[pp] = mlB[pp * 32 + row];
                    lp[pp] = mlB[pp * 32 + 16 + row];
                    mt = fmaxf(mt, mp[pp]);
                }
                const float f0 = exp2a(m[j] - mt);
                float fp[3];
#pragma unroll
                for (int pp = 0; pp < 3; pp++) fp[pp] = exp2a(mp[pp] - mt);
                const float inv = 1.0f / (l[j] * f0 + lp[0] * fp[0] + lp[1] * fp[1] + lp[2] * fp[2]);
#pragma unroll
                for (int h = 0; h < 8; h++) {
                    float acc = o[h][j] * f0;
#pragma unroll
                    for (int pp = 0; pp < 3; pp++)
                        acc += oB[pp * 2048 + row * 128 + h * 16 + lo] * fp[pp];
                    ob[row * HD + h * 16 + lo] = acc * inv;
                }
            }
        }
        __syncthreads();   // scratch consumed before phase-2 staging
        asm volatile("s_waitcnt vmcnt(0)" ::: "memory");  // drain stores: keep counts exact
    }
#undef KSTAGE
#undef VLOAD
#undef ABODY
}

extern "C" void kernel_launch(void* const* d_in, const int* in_sizes, int n_in,
                              void* d_out, int out_size, void* d_ws, size_t ws_size,
                              hipStream_t stream) {
    const float* x  = (const float*)d_in[0];
    const float* Wq = (const float*)d_in[1];
    const float* Wk = (const float*)d_in[2];
    const float* Wv = (const float*)d_in[3];

    // ws: Wt 768KB | q 4MB | k 4MB | Vt (padded) 4.06MB
    ushort* Wt = (ushort*)d_ws;
    ushort* qw = (ushort*)((char*)d_ws + 786432);
    ushort* kw = qw + (size_t)BATCH * CTX * HD;
    ushort* vw = kw + (size_t)BATCH * CTX * HD;

    wt_kernel<<<dim3(EMB / 64, HD / 64, 3), 256, 0, stream>>>(Wq, Wk, Wv, Wt);
    proj_kernel<<<dim3(512, 2), 256, 0, stream>>>(x, Wt, qw, kw, vw);
    attn_kernel<<<512, 256, 0, stream>>>(qw, kw, vw, (float*)d_out);
}

// Round 27
// 82.283 us; speedup vs baseline: 1.1401x; 1.1401x over previous
//
#include <hip/hip_runtime.h>
#include <hip/hip_bf16.h>

#define BATCH 8
#define CTX   2048
#define EMB   1024
#define HD    128
#define VSTR  2080   // Vt row stride (elems)

using bf16x8 = __attribute__((ext_vector_type(8))) short;
using fx4    = __attribute__((ext_vector_type(4))) float;

__device__ __forceinline__ ushort f2bf(float f) {
    union { float f; unsigned u; } v; v.f = f;
    unsigned u = v.u;
    u += 0x7fffu + ((u >> 16) & 1u);   // RNE
    return (ushort)(u >> 16);
}

__device__ __forceinline__ unsigned cvtpk(float a, float b) {
    unsigned r;
    asm("v_cvt_pk_bf16_f32 %0, %1, %2" : "=v"(r) : "v"(a), "v"(b));
    return r;
}

__device__ __forceinline__ float exp2a(float x) {   // v_exp_f32 = 2^x
    float r;
    asm("v_exp_f32 %0, %1" : "=v"(r) : "v"(x));
    return r;
}

__device__ __forceinline__ void gload16(const void* g, void* l) {
    __builtin_amdgcn_global_load_lds(
        (const __attribute__((address_space(1))) unsigned*)g,
        (__attribute__((address_space(3))) unsigned*)l, 16, 0, 0);
}

// ---------------- kernel 1: W (E,H) fp32 -> Wt (3,H,E) bf16 (LDS transpose) -
__global__ __launch_bounds__(256) void wt_kernel(
        const float* __restrict__ Wq, const float* __restrict__ Wk,
        const float* __restrict__ Wv, ushort* __restrict__ Wt) {
    __shared__ ushort lds[64][65];
    const int w  = blockIdx.z;
    const int e0 = blockIdx.x * 64;
    const int h0 = blockIdx.y * 64;
    const float* W = (w == 0) ? Wq : (w == 1) ? Wk : Wv;
    const int tl = threadIdx.x & 63;
    const int tg = threadIdx.x >> 6;
#pragma unroll
    for (int rr = 0; rr < 16; ++rr) {
        const int el = rr * 4 + tg;
        lds[el][tl] = f2bf(W[(size_t)(e0 + el) * HD + h0 + tl]);
    }
    __syncthreads();
#pragma unroll
    for (int rr = 0; rr < 16; ++rr) {
        const int hl = rr * 4 + tg;
        Wt[((size_t)w * HD + h0 + hl) * EMB + e0 + tl] = lds[tl][hl];
    }
}

// ---------------- kernel 2: projection v7 (split counted vmcnt) -------------
// A dbuf staged after barrier; B wave-aligned single-buffered; exact counted
// waits (FIFO: A=2 then B=6 per thread, steady-state 8 outstanding):
//   top: vmcnt(6) drains exactly A(i); mid: vmcnt(2) drains exactly B(i).
__global__ __launch_bounds__(256) void proj_kernel(
        const float* __restrict__ x, const ushort* __restrict__ Wt,
        ushort* __restrict__ q, ushort* __restrict__ k, ushort* __restrict__ vt) {
    __shared__ __align__(16) float  As[2][32 * 64];   // 16 KB (dbuf)
    __shared__ __align__(16) ushort Bs[192 * 64];     // 24 KB (single, wave-split)

    const int t    = threadIdx.x;
    const int wave = t >> 6;
    const int lane = t & 63;
    const int lo = lane & 15, hi = lane >> 4;
    const int brow = blockIdx.x * 32;
    const int bcol = blockIdx.y * 192;
    const int kph  = (blockIdx.x ^ (blockIdx.y << 3)) & 15;   // stagger

    fx4 acc[2][3];
#pragma unroll
    for (int m2 = 0; m2 < 2; m2++)
#pragma unroll
        for (int n = 0; n < 3; n++) acc[m2][n] = fx4{0.f, 0.f, 0.f, 0.f};

    const int arow_s = t >> 4;
    const int acol_s = ((t & 15) ^ (arow_s & 7)) << 2;        // f32 elems
    const char* Bw = (const char*)Bs + wave * 6144;

#define ASTAGE(bi, k0_) do {                                                    \
    _Pragma("unroll")                                                           \
    for (int r = 0; r < 2; ++r)                                                 \
        gload16(x + (size_t)(brow + r * 16 + arow_s) * EMB + (k0_) + acol_s,    \
                (char*)As[bi] + r * 4096 + wave * 1024);                        \
} while (0)

#define BSTAGE(k0_) do {                                                        \
    _Pragma("unroll")                                                           \
    for (int r = 0; r < 6; ++r) {                                               \
        const int ci  = r * 64 + lane;                                          \
        const int rowL = ci >> 3;                                               \
        const int slot = (ci & 7) ^ (rowL & 7);                                 \
        gload16(Wt + (size_t)(bcol + wave * 48 + rowL) * EMB + (k0_) + (slot << 3), \
                (char*)Bs + wave * 6144 + r * 1024);                            \
    }                                                                           \
} while (0)

    // prologue: A(0) then B(0)  (FIFO order matters for the counted waits)
    {
        const int k0 = (kph & 15) << 6;
        ASTAGE(0, k0);
        BSTAGE(k0);
    }

    for (int i = 0; i < 16; ++i) {
        // drain exactly A(i) (oldest 2 of 8); B(i) stays in flight
        asm volatile("s_waitcnt vmcnt(6)" ::: "memory");
        __builtin_amdgcn_sched_barrier(0);
        __builtin_amdgcn_s_barrier();          // A(i) visible to all waves
        __builtin_amdgcn_sched_barrier(0);

        // stage A(i+1) (its buffer's reads retired before barrier(i))
        if (i + 1 < 16) ASTAGE((i + 1) & 1, (((i + 1 + kph) & 15) << 6));

        const char* Ab = (const char*)As[i & 1];
        // ---- A fragments (both ks slices) ----
        bf16x8 afr[2][2];
#pragma unroll
        for (int m2 = 0; m2 < 2; m2++) {
            const int rowA = m2 * 16 + lo;
            const unsigned sw = (rowA & 7) << 4;
#pragma unroll
            for (int ks2 = 0; ks2 < 2; ks2++) {
                const unsigned ub = rowA * 256 + ks2 * 128 + hi * 32;
                fx4 a0 = *(const fx4*)(Ab + (ub ^ sw));
                fx4 a1 = *(const fx4*)(Ab + ((ub + 16) ^ sw));
                union { unsigned u[4]; bf16x8 v; } pk;
                pk.u[0] = cvtpk(a0[0], a0[1]);
                pk.u[1] = cvtpk(a0[2], a0[3]);
                pk.u[2] = cvtpk(a1[0], a1[1]);
                pk.u[3] = cvtpk(a1[2], a1[3]);
                afr[m2][ks2] = pk.v;
            }
        }
        // drain exactly B(i); A(i+1) (if issued) stays in flight
        if (i + 1 < 16) asm volatile("s_waitcnt vmcnt(2)" ::: "memory");
        else            asm volatile("s_waitcnt vmcnt(0)" ::: "memory");
        __builtin_amdgcn_sched_barrier(0);

        bf16x8 bfr[2][3];
#pragma unroll
        for (int ks2 = 0; ks2 < 2; ks2++)
#pragma unroll
            for (int n = 0; n < 3; n++) {
                const int rowL = n * 16 + lo;               // key = lo&7
                const unsigned ub = rowL * 128 + ks2 * 64 + hi * 16;
                bfr[ks2][n] = *(const bf16x8*)(Bw + (ub ^ ((lo & 7) << 4)));
            }
        // all ds_reads landed -> safe to overwrite this wave's B region
        asm volatile("s_waitcnt lgkmcnt(0)" ::: "memory");
        __builtin_amdgcn_sched_barrier(0);
        if (i + 1 < 16) BSTAGE((((i + 1 + kph) & 15) << 6));
        __builtin_amdgcn_sched_barrier(0);

        __builtin_amdgcn_s_setprio(1);
#pragma unroll
        for (int ks2 = 0; ks2 < 2; ks2++)
#pragma unroll
            for (int m2 = 0; m2 < 2; m2++)
#pragma unroll
                for (int n = 0; n < 3; n++)
                    acc[m2][n] = __builtin_amdgcn_mfma_f32_16x16x32_bf16(
                        afr[m2][ks2], bfr[ks2][n], acc[m2][n], 0, 0, 0);
        __builtin_amdgcn_s_setprio(0);
    }
#undef ASTAGE
#undef BSTAGE

    const float qscale = 0.045084219f;   // (1/sqrt(1024)) * log2(e)
#pragma unroll
    for (int n = 0; n < 3; n++) {
        const int col = bcol + wave * 48 + n * 16 + lo;
        const int bnn = col >> 7;
        const int cc  = col & 127;
#pragma unroll
        for (int m2 = 0; m2 < 2; m2++) {
#pragma unroll
            for (int j = 0; j < 4; j++) {
                const int r = brow + m2 * 16 + hi * 4 + j;
                if (bnn == 0)      q[(size_t)r * HD + cc] = f2bf(acc[m2][n][j] * qscale);
                else if (bnn == 1) k[(size_t)r * HD + cc] = f2bf(acc[m2][n][j]);
                else {
                    const int bb2 = r >> 11, ccc = r & (CTX - 1);
                    vt[((size_t)bb2 * HD + cc) * VSTR + ccc] = f2bf(acc[m2][n][j]);
                }
            }
        }
    }
}

// ---------------- kernel 3: attention v10 (balanced 2-phase, 4-way KV) ------
// 512 blocks x 4 waves, 2 blocks/CU exact fill = 8 waves/CU SUSTAINED.
// Block p runs q-tile (127-p) then p -> every block 17-18 KV iterations.
// Each iter = 128-wide KV stripe; wave w owns cols [w*32, w*32+32) with a
// private K double-buffer (no barriers in loop, counted vmcnt only).
// 4-partial merge per phase via LDS; phase-end vmcnt(0) drains out-stores.
__global__ __launch_bounds__(256) void attn_kernel(
        const ushort* __restrict__ q, const ushort* __restrict__ k,
        const ushort* __restrict__ vt, float* __restrict__ out) {
    __shared__ __align__(16) char Ks[2][4][8192];  // [buf][wave][32 rows x 256B]
    __shared__ __align__(16) char p_lds[4][1280];  // per-wave P [16][80B]

    const int id   = blockIdx.x;
    const int b    = id & 7;                      // one batch per XCD
    const int p    = id >> 3;                     // 0..63
    const int t    = threadIdx.x;
    const int w    = t >> 6;                      // wave = kv column quarter
    const int lane = t & 63;
    const int lo = lane & 15, hi = lane >> 4;

    const ushort* qb = q  + (size_t)b * CTX * HD;
    const ushort* kb = k  + (size_t)b * CTX * HD;
    const ushort* vb = vt + (size_t)b * HD * VSTR;

    // merge scratch (aliases Ks buf0 areas; only touched after loop + sync)
    float* oB  = (float*)&Ks[0][0][0];    // [3][16][128] f32 = 24 KB
    float* mlB = (float*)&Ks[0][3][0];    // [3][2][16] f32

#define KSTAGE(bi, kv0_) do {                                                  \
    _Pragma("unroll")                                                          \
    for (int r = 0; r < 8; ++r) {                                              \
        const int rl  = r * 4 + (lane >> 4);                                   \
        const int key = (rl >> 1) & 7;                                         \
        gload16(kb + (size_t)((kv0_) + w * 32 + rl) * HD + (((lane & 15) ^ key) << 3), \
                Ks[bi][w] + r * 1024);                                         \
    }                                                                          \
} while (0)

    for (int phase = 0; phase < 2; ++phase) {
        const int qt = phase ? p : (127 - p);
        const int q0 = qt * 16;
        const int nkv = qt / 8 + 1;

        bf16x8 qf[4];
#pragma unroll
        for (int ks = 0; ks < 4; ks++)
            qf[ks] = *(const bf16x8*)(qb + (size_t)(q0 + lo) * HD + ks * 32 + hi * 8);

        fx4 o[8];
#pragma unroll
        for (int h = 0; h < 8; h++) o[h] = fx4{0.f, 0.f, 0.f, 0.f};
        float m[4], l[4];
#pragma unroll
        for (int j = 0; j < 4; j++) { m[j] = 0.f; l[j] = 0.f; }

        KSTAGE(0, 0);

        for (int it = 0; it < nkv; ++it) {
            const int kv0 = it * 128;
            // ---- V loads, global->reg (compiler guards vf before PV) ----
            bf16x8 vf[8];
#pragma unroll
            for (int h = 0; h < 8; h++)
                vf[h] = *(const bf16x8*)(vb + (size_t)(h * 16 + lo) * VSTR + kv0 + w * 32 + hi * 8);
            __builtin_amdgcn_sched_barrier(0);
            // ---- stage next K tile; counted wait for K(it) (NEVER 0) ----
            if (it + 1 < nkv) {
                KSTAGE((it + 1) & 1, kv0 + 128);
                __builtin_amdgcn_sched_barrier(0);
                asm volatile("s_waitcnt vmcnt(16)" ::: "memory");  // newer: V8+K8
            } else {
                asm volatile("s_waitcnt vmcnt(8)" ::: "memory");   // newer: V8
            }
            __builtin_amdgcn_sched_barrier(0);

            const char* Kb = Ks[it & 1][w];
            // ---- S = Q K^T; lane lo owns local kv rows (2lo, 2lo+1) ----
            fx4 s[2];
            s[0] = fx4{0.f, 0.f, 0.f, 0.f};
            s[1] = fx4{0.f, 0.f, 0.f, 0.f};
            __builtin_amdgcn_s_setprio(1);
#pragma unroll
            for (int n2 = 0; n2 < 2; n2++) {
                const int rl = 2 * lo + n2;
#pragma unroll
                for (int ks = 0; ks < 4; ks++) {
                    bf16x8 kf = *(const bf16x8*)(Kb + rl * 256 + ((ks * 64 + hi * 16) ^ ((lo & 7) << 4)));
                    s[n2] = __builtin_amdgcn_mfma_f32_16x16x32_bf16(qf[ks], kf, s[n2], 0, 0, 0);
                }
            }
            __builtin_amdgcn_s_setprio(0);

            const bool diag = (kv0 + 128 > q0);
            // ---- mask + defer-max overflow check (lane-local, exp2) ----
            float pmax[4];
            int allok = 1;
#pragma unroll
            for (int j = 0; j < 4; j++) {
                const int r = q0 + hi * 4 + j;
                if (diag) {
                    const int c0 = kv0 + w * 32 + 2 * lo;
                    if (c0 > r)     s[0][j] = -INFINITY;
                    if (c0 + 1 > r) s[1][j] = -INFINITY;
                }
                pmax[j] = fmaxf(s[0][j], s[1][j]);
                allok &= (pmax[j] <= m[j] + 23.0f);
            }
            if (!__all(allok)) {
                // slow path (rare): full cross-lane max + rescale
#pragma unroll
                for (int j = 0; j < 4; j++) {
                    float mx = pmax[j];
                    mx = fmaxf(mx, __shfl_xor(mx, 1));
                    mx = fmaxf(mx, __shfl_xor(mx, 2));
                    mx = fmaxf(mx, __shfl_xor(mx, 4));
                    mx = fmaxf(mx, __shfl_xor(mx, 8));
                    const float mn = fmaxf(m[j], mx);
                    const float f  = exp2a(m[j] - mn);
                    l[j] *= f;
#pragma unroll
                    for (int h = 0; h < 8; h++) o[h][j] *= f;
                    m[j] = mn;
                }
            }
            // ---- fast exp2 + lane-local l + packed P write ----
#pragma unroll
            for (int j = 0; j < 4; j++) {
                const float p0 = exp2a(s[0][j] - m[j]);
                const float p1 = exp2a(s[1][j] - m[j]);
                l[j] += p0 + p1;
                *(unsigned*)(p_lds[w] + (hi * 4 + j) * 80 + lo * 4) = cvtpk(p0, p1);
            }
            asm volatile("" ::: "memory");
            // ---- PV: A = P (16x32, 80B stride), B = V regs ----
            bf16x8 pa = *(const bf16x8*)(p_lds[w] + lo * 80 + hi * 16);
            __builtin_amdgcn_s_setprio(1);
#pragma unroll
            for (int h = 0; h < 8; h++)
                o[h] = __builtin_amdgcn_mfma_f32_16x16x32_bf16(pa, vf[h], o[h], 0, 0, 0);
            __builtin_amdgcn_s_setprio(0);
        }

        // ---- cross-lane l reduce (16-lane groups) ----
#pragma unroll
        for (int j = 0; j < 4; j++) {
            l[j] += __shfl_xor(l[j], 1);
            l[j] += __shfl_xor(l[j], 2);
            l[j] += __shfl_xor(l[j], 4);
            l[j] += __shfl_xor(l[j], 8);
        }

        // ---- merge the four kv-quarter partials ----
        __syncthreads();   // all waves done with Ks reads
        if (w > 0) {
#pragma unroll
            for (int j = 0; j < 4; j++) {
                const int row = hi * 4 + j;
                if (lo == 0) { mlB[(w - 1) * 32 + row] = m[j]; mlB[(w - 1) * 32 + 16 + row] = l[j]; }
#pragma unroll
                for (int h = 0; h < 8; h++)
                    oB[(w - 1) * 2048 + row * 128 + h * 16 + lo] = o[h][j];
            }
        }
        __syncthreads();
        if (w == 0) {
            float* ob = out + ((size_t)b * CTX + q0) * HD;
#pragma unroll
            for (int j = 0; j < 4; j++) {
                const int row = hi * 4 + j;
                float mp[3], lp[3];
                float mt = m[j];
#pragma unroll
                for (int pp = 0; pp < 3; pp++) {
                    mp[pp] = mlB[pp * 32 + row];
                    lp[pp] = mlB[pp * 32 + 16 + row];
                    mt = fmaxf(mt, mp[pp]);
                }
                const float f0 = exp2a(m[j] - mt);
                float fp[3];
#pragma unroll
                for (int pp = 0; pp < 3; pp++) fp[pp] = exp2a(mp[pp] - mt);
                const float inv = 1.0f / (l[j] * f0 + lp[0] * fp[0] + lp[1] * fp[1] + lp[2] * fp[2]);
#pragma unroll
                for (int h = 0; h < 8; h++) {
                    float acc = o[h][j] * f0;
#pragma unroll
                    for (int pp = 0; pp < 3; pp++)
                        acc += oB[pp * 2048 + row * 128 + h * 16 + lo] * fp[pp];
                    ob[row * HD + h * 16 + lo] = acc * inv;
                }
            }
        }
        __syncthreads();   // scratch consumed before phase-2 staging
        asm volatile("s_waitcnt vmcnt(0)" ::: "memory");  // drain stores: keep counts exact
    }
#undef KSTAGE
}

extern "C" void kernel_launch(void* const* d_in, const int* in_sizes, int n_in,
                              void* d_out, int out_size, void* d_ws, size_t ws_size,
                              hipStream_t stream) {
    const float* x  = (const float*)d_in[0];
    const float* Wq = (const float*)d_in[1];
    const float* Wk = (const float*)d_in[2];
    const float* Wv = (const float*)d_in[3];

    // ws: Wt 768KB | q 4MB | k 4MB | Vt (padded) 4.06MB
    ushort* Wt = (ushort*)d_ws;
    ushort* qw = (ushort*)((char*)d_ws + 786432);
    ushort* kw = qw + (size_t)BATCH * CTX * HD;
    ushort* vw = kw + (size_t)BATCH * CTX * HD;

    wt_kernel<<<dim3(EMB / 64, HD / 64, 3), 256, 0, stream>>>(Wq, Wk, Wv, Wt);
    proj_kernel<<<dim3(512, 2), 256, 0, stream>>>(x, Wt, qw, kw, vw);
    attn_kernel<<<512, 256, 0, stream>>>(qw, kw, vw, (float*)d_out);
}

// Round 28
// 82.236 us; speedup vs baseline: 1.1407x; 1.0006x over previous
//
#include <hip/hip_runtime.h>
#include <hip/hip_bf16.h>

#define BATCH 8
#define CTX   2048
#define EMB   1024
#define HD    128
#define VSTR  2080   // Vt row stride (elems)

using bf16x8 = __attribute__((ext_vector_type(8))) short;
using fx4    = __attribute__((ext_vector_type(4))) float;

__device__ __forceinline__ ushort f2bf(float f) {
    union { float f; unsigned u; } v; v.f = f;
    unsigned u = v.u;
    u += 0x7fffu + ((u >> 16) & 1u);   // RNE
    return (ushort)(u >> 16);
}

__device__ __forceinline__ unsigned cvtpk(float a, float b) {
    unsigned r;
    asm("v_cvt_pk_bf16_f32 %0, %1, %2" : "=v"(r) : "v"(a), "v"(b));
    return r;
}

__device__ __forceinline__ float exp2a(float x) {   // v_exp_f32 = 2^x
    float r;
    asm("v_exp_f32 %0, %1" : "=v"(r) : "v"(x));
    return r;
}

__device__ __forceinline__ void gload16(const void* g, void* l) {
    __builtin_amdgcn_global_load_lds(
        (const __attribute__((address_space(1))) unsigned*)g,
        (__attribute__((address_space(3))) unsigned*)l, 16, 0, 0);
}

// ---------------- kernel 1: W (E,H) fp32 -> Wt (3,H,E) bf16 (LDS transpose) -
__global__ __launch_bounds__(256) void wt_kernel(
        const float* __restrict__ Wq, const float* __restrict__ Wk,
        const float* __restrict__ Wv, ushort* __restrict__ Wt) {
    __shared__ ushort lds[64][65];
    const int w  = blockIdx.z;
    const int e0 = blockIdx.x * 64;
    const int h0 = blockIdx.y * 64;
    const float* W = (w == 0) ? Wq : (w == 1) ? Wk : Wv;
    const int tl = threadIdx.x & 63;
    const int tg = threadIdx.x >> 6;
#pragma unroll
    for (int rr = 0; rr < 16; ++rr) {
        const int el = rr * 4 + tg;
        lds[el][tl] = f2bf(W[(size_t)(e0 + el) * HD + h0 + tl]);
    }
    __syncthreads();
#pragma unroll
    for (int rr = 0; rr < 16; ++rr) {
        const int hl = rr * 4 + tg;
        Wt[((size_t)w * HD + h0 + hl) * EMB + e0 + tl] = lds[tl][hl];
    }
}

// ---------------- kernel 2: projection v7 (split counted vmcnt) -------------
// A dbuf staged after barrier; B wave-aligned single-buffered; exact counted
// waits (FIFO: A=2 then B=6 per thread, steady-state 8 outstanding):
//   top: vmcnt(6) drains exactly A(i); mid: vmcnt(2) drains exactly B(i).
__global__ __launch_bounds__(256) void proj_kernel(
        const float* __restrict__ x, const ushort* __restrict__ Wt,
        ushort* __restrict__ q, ushort* __restrict__ k, ushort* __restrict__ vt) {
    __shared__ __align__(16) float  As[2][32 * 64];   // 16 KB (dbuf)
    __shared__ __align__(16) ushort Bs[192 * 64];     // 24 KB (single, wave-split)

    const int t    = threadIdx.x;
    const int wave = t >> 6;
    const int lane = t & 63;
    const int lo = lane & 15, hi = lane >> 4;
    const int brow = blockIdx.x * 32;
    const int bcol = blockIdx.y * 192;
    const int kph  = (blockIdx.x ^ (blockIdx.y << 3)) & 15;   // stagger

    fx4 acc[2][3];
#pragma unroll
    for (int m2 = 0; m2 < 2; m2++)
#pragma unroll
        for (int n = 0; n < 3; n++) acc[m2][n] = fx4{0.f, 0.f, 0.f, 0.f};

    const int arow_s = t >> 4;
    const int acol_s = ((t & 15) ^ (arow_s & 7)) << 2;        // f32 elems
    const char* Bw = (const char*)Bs + wave * 6144;

#define ASTAGE(bi, k0_) do {                                                    \
    _Pragma("unroll")                                                           \
    for (int r = 0; r < 2; ++r)                                                 \
        gload16(x + (size_t)(brow + r * 16 + arow_s) * EMB + (k0_) + acol_s,    \
                (char*)As[bi] + r * 4096 + wave * 1024);                        \
} while (0)

#define BSTAGE(k0_) do {                                                        \
    _Pragma("unroll")                                                           \
    for (int r = 0; r < 6; ++r) {                                               \
        const int ci  = r * 64 + lane;                                          \
        const int rowL = ci >> 3;                                               \
        const int slot = (ci & 7) ^ (rowL & 7);                                 \
        gload16(Wt + (size_t)(bcol + wave * 48 + rowL) * EMB + (k0_) + (slot << 3), \
                (char*)Bs + wave * 6144 + r * 1024);                            \
    }                                                                           \
} while (0)

    // prologue: A(0) then B(0)  (FIFO order matters for the counted waits)
    {
        const int k0 = (kph & 15) << 6;
        ASTAGE(0, k0);
        BSTAGE(k0);
    }

    for (int i = 0; i < 16; ++i) {
        // drain exactly A(i) (oldest 2 of 8); B(i) stays in flight
        asm volatile("s_waitcnt vmcnt(6)" ::: "memory");
        __builtin_amdgcn_sched_barrier(0);
        __builtin_amdgcn_s_barrier();          // A(i) visible to all waves
        __builtin_amdgcn_sched_barrier(0);

        // stage A(i+1) (its buffer's reads retired before barrier(i))
        if (i + 1 < 16) ASTAGE((i + 1) & 1, (((i + 1 + kph) & 15) << 6));

        const char* Ab = (const char*)As[i & 1];
        // ---- A fragments (both ks slices) ----
        bf16x8 afr[2][2];
#pragma unroll
        for (int m2 = 0; m2 < 2; m2++) {
            const int rowA = m2 * 16 + lo;
            const unsigned sw = (rowA & 7) << 4;
#pragma unroll
            for (int ks2 = 0; ks2 < 2; ks2++) {
                const unsigned ub = rowA * 256 + ks2 * 128 + hi * 32;
                fx4 a0 = *(const fx4*)(Ab + (ub ^ sw));
                fx4 a1 = *(const fx4*)(Ab + ((ub + 16) ^ sw));
                union { unsigned u[4]; bf16x8 v; } pk;
                pk.u[0] = cvtpk(a0[0], a0[1]);
                pk.u[1] = cvtpk(a0[2], a0[3]);
                pk.u[2] = cvtpk(a1[0], a1[1]);
                pk.u[3] = cvtpk(a1[2], a1[3]);
                afr[m2][ks2] = pk.v;
            }
        }
        // drain exactly B(i); A(i+1) (if issued) stays in flight
        if (i + 1 < 16) asm volatile("s_waitcnt vmcnt(2)" ::: "memory");
        else            asm volatile("s_waitcnt vmcnt(0)" ::: "memory");
        __builtin_amdgcn_sched_barrier(0);

        bf16x8 bfr[2][3];
#pragma unroll
        for (int ks2 = 0; ks2 < 2; ks2++)
#pragma unroll
            for (int n = 0; n < 3; n++) {
                const int rowL = n * 16 + lo;               // key = lo&7
                const unsigned ub = rowL * 128 + ks2 * 64 + hi * 16;
                bfr[ks2][n] = *(const bf16x8*)(Bw + (ub ^ ((lo & 7) << 4)));
            }
        // all ds_reads landed -> safe to overwrite this wave's B region
        asm volatile("s_waitcnt lgkmcnt(0)" ::: "memory");
        __builtin_amdgcn_sched_barrier(0);
        if (i + 1 < 16) BSTAGE((((i + 1 + kph) & 15) << 6));
        __builtin_amdgcn_sched_barrier(0);

        __builtin_amdgcn_s_setprio(1);
#pragma unroll
        for (int ks2 = 0; ks2 < 2; ks2++)
#pragma unroll
            for (int m2 = 0; m2 < 2; m2++)
#pragma unroll
                for (int n = 0; n < 3; n++)
                    acc[m2][n] = __builtin_amdgcn_mfma_f32_16x16x32_bf16(
                        afr[m2][ks2], bfr[ks2][n], acc[m2][n], 0, 0, 0);
        __builtin_amdgcn_s_setprio(0);
    }
#undef ASTAGE
#undef BSTAGE

    const float qscale = 0.045084219f;   // (1/sqrt(1024)) * log2(e)
#pragma unroll
    for (int n = 0; n < 3; n++) {
        const int col = bcol + wave * 48 + n * 16 + lo;
        const int bnn = col >> 7;
        const int cc  = col & 127;
#pragma unroll
        for (int m2 = 0; m2 < 2; m2++) {
#pragma unroll
            for (int j = 0; j < 4; j++) {
                const int r = brow + m2 * 16 + hi * 4 + j;
                if (bnn == 0)      q[(size_t)r * HD + cc] = f2bf(acc[m2][n][j] * qscale);
                else if (bnn == 1) k[(size_t)r * HD + cc] = f2bf(acc[m2][n][j]);
                else {
                    const int bb2 = r >> 11, ccc = r & (CTX - 1);
                    vt[((size_t)bb2 * HD + cc) * VSTR + ccc] = f2bf(acc[m2][n][j]);
                }
            }
        }
    }
}

// ---------------- kernel 3: attention v10c (wave-parallel merge) ------------
// As v10 (512 blocks x 4 waves, 2-phase serpentine, private K dbuf,
// barrier-free counted-vmcnt loop) but the per-phase merge epilogue is
// parallelized 4-ways: ALL waves write their (o,m,l) partials to LDS, then
// each wave merges and stores its own 32 output columns (h = 2w, 2w+1).
// oB row stride padded to 132 f32 (rows spread across banks).
__global__ __launch_bounds__(256) void attn_kernel(
        const ushort* __restrict__ q, const ushort* __restrict__ k,
        const ushort* __restrict__ vt, float* __restrict__ out) {
    __shared__ __align__(16) char Ks[2][4][8192];  // [buf][wave][32 rows x 256B]
    __shared__ __align__(16) char p_lds[4][1280];  // per-wave P [16][80B]

    const int id   = blockIdx.x;
    const int b    = id & 7;                      // one batch per XCD
    const int p    = id >> 3;                     // 0..63
    const int t    = threadIdx.x;
    const int w    = t >> 6;                      // wave = kv column quarter
    const int lane = t & 63;
    const int lo = lane & 15, hi = lane >> 4;

    const ushort* qb = q  + (size_t)b * CTX * HD;
    const ushort* kb = k  + (size_t)b * CTX * HD;
    const ushort* vb = vt + (size_t)b * HD * VSTR;

    // merge scratch aliases Ks (touched only after loop + syncthreads):
    // oB [4][16][132] f32 = 33792 B; mlB [4][2][16] f32 at +33792.
    float* oB  = (float*)&Ks[0][0][0];
    float* mlB = (float*)((char*)&Ks[0][0][0] + 33792);

#define KSTAGE(bi, kv0_) do {                                                  \
    _Pragma("unroll")                                                          \
    for (int r = 0; r < 8; ++r) {                                              \
        const int rl  = r * 4 + (lane >> 4);                                   \
        const int key = (rl >> 1) & 7;                                         \
        gload16(kb + (size_t)((kv0_) + w * 32 + rl) * HD + (((lane & 15) ^ key) << 3), \
                Ks[bi][w] + r * 1024);                                         \
    }                                                                          \
} while (0)

    for (int phase = 0; phase < 2; ++phase) {
        const int qt = phase ? p : (127 - p);
        const int q0 = qt * 16;
        const int nkv = qt / 8 + 1;

        bf16x8 qf[4];
#pragma unroll
        for (int ks = 0; ks < 4; ks++)
            qf[ks] = *(const bf16x8*)(qb + (size_t)(q0 + lo) * HD + ks * 32 + hi * 8);

        fx4 o[8];
#pragma unroll
        for (int h = 0; h < 8; h++) o[h] = fx4{0.f, 0.f, 0.f, 0.f};
        float m[4], l[4];
#pragma unroll
        for (int j = 0; j < 4; j++) { m[j] = 0.f; l[j] = 0.f; }

        KSTAGE(0, 0);

        for (int it = 0; it < nkv; ++it) {
            const int kv0 = it * 128;
            // ---- V loads, global->reg (compiler guards vf before PV) ----
            bf16x8 vf[8];
#pragma unroll
            for (int h = 0; h < 8; h++)
                vf[h] = *(const bf16x8*)(vb + (size_t)(h * 16 + lo) * VSTR + kv0 + w * 32 + hi * 8);
            __builtin_amdgcn_sched_barrier(0);
            // ---- stage next K tile; counted wait for K(it) (NEVER 0) ----
            if (it + 1 < nkv) {
                KSTAGE((it + 1) & 1, kv0 + 128);
                __builtin_amdgcn_sched_barrier(0);
                asm volatile("s_waitcnt vmcnt(16)" ::: "memory");  // newer: V8+K8
            } else {
                asm volatile("s_waitcnt vmcnt(8)" ::: "memory");   // newer: V8
            }
            __builtin_amdgcn_sched_barrier(0);

            const char* Kb = Ks[it & 1][w];
            // ---- S = Q K^T; lane lo owns local kv rows (2lo, 2lo+1) ----
            fx4 s[2];
            s[0] = fx4{0.f, 0.f, 0.f, 0.f};
            s[1] = fx4{0.f, 0.f, 0.f, 0.f};
            __builtin_amdgcn_s_setprio(1);
#pragma unroll
            for (int n2 = 0; n2 < 2; n2++) {
                const int rl = 2 * lo + n2;
#pragma unroll
                for (int ks = 0; ks < 4; ks++) {
                    bf16x8 kf = *(const bf16x8*)(Kb + rl * 256 + ((ks * 64 + hi * 16) ^ ((lo & 7) << 4)));
                    s[n2] = __builtin_amdgcn_mfma_f32_16x16x32_bf16(qf[ks], kf, s[n2], 0, 0, 0);
                }
            }
            __builtin_amdgcn_s_setprio(0);

            const bool diag = (kv0 + 128 > q0);
            // ---- mask + defer-max overflow check (lane-local, exp2) ----
            float pmax[4];
            int allok = 1;
#pragma unroll
            for (int j = 0; j < 4; j++) {
                const int r = q0 + hi * 4 + j;
                if (diag) {
                    const int c0 = kv0 + w * 32 + 2 * lo;
                    if (c0 > r)     s[0][j] = -INFINITY;
                    if (c0 + 1 > r) s[1][j] = -INFINITY;
                }
                pmax[j] = fmaxf(s[0][j], s[1][j]);
                allok &= (pmax[j] <= m[j] + 23.0f);
            }
            if (!__all(allok)) {
                // slow path (rare): full cross-lane max + rescale
#pragma unroll
                for (int j = 0; j < 4; j++) {
                    float mx = pmax[j];
                    mx = fmaxf(mx, __shfl_xor(mx, 1));
                    mx = fmaxf(mx, __shfl_xor(mx, 2));
                    mx = fmaxf(mx, __shfl_xor(mx, 4));
                    mx = fmaxf(mx, __shfl_xor(mx, 8));
                    const float mn = fmaxf(m[j], mx);
                    const float f  = exp2a(m[j] - mn);
                    l[j] *= f;
#pragma unroll
                    for (int h = 0; h < 8; h++) o[h][j] *= f;
                    m[j] = mn;
                }
            }
            // ---- fast exp2 + lane-local l + packed P write ----
#pragma unroll
            for (int j = 0; j < 4; j++) {
                const float p0 = exp2a(s[0][j] - m[j]);
                const float p1 = exp2a(s[1][j] - m[j]);
                l[j] += p0 + p1;
                *(unsigned*)(p_lds[w] + (hi * 4 + j) * 80 + lo * 4) = cvtpk(p0, p1);
            }
            asm volatile("" ::: "memory");
            // ---- PV: A = P (16x32, 80B stride), B = V regs ----
            bf16x8 pa = *(const bf16x8*)(p_lds[w] + lo * 80 + hi * 16);
            __builtin_amdgcn_s_setprio(1);
#pragma unroll
            for (int h = 0; h < 8; h++)
                o[h] = __builtin_amdgcn_mfma_f32_16x16x32_bf16(pa, vf[h], o[h], 0, 0, 0);
            __builtin_amdgcn_s_setprio(0);
        }

        // ---- cross-lane l reduce (16-lane groups) ----
#pragma unroll
        for (int j = 0; j < 4; j++) {
            l[j] += __shfl_xor(l[j], 1);
            l[j] += __shfl_xor(l[j], 2);
            l[j] += __shfl_xor(l[j], 4);
            l[j] += __shfl_xor(l[j], 8);
        }

        // ---- wave-parallel merge: all waves write partials ----
        __syncthreads();   // all waves done with Ks reads
#pragma unroll
        for (int j = 0; j < 4; j++) {
            const int row = hi * 4 + j;
            if (lo == 0) { mlB[w * 32 + row] = m[j]; mlB[w * 32 + 16 + row] = l[j]; }
#pragma unroll
            for (int h = 0; h < 8; h++)
                oB[w * 2112 + row * 132 + h * 16 + lo] = o[h][j];
        }
        __syncthreads();
        // ---- each wave merges + stores its own columns h = 2w, 2w+1 ----
        {
            float* ob = out + ((size_t)b * CTX + q0) * HD;
#pragma unroll
            for (int j = 0; j < 4; j++) {
                const int row = hi * 4 + j;
                float mp[4], lp[4];
                float mt = -INFINITY;
#pragma unroll
                for (int pp = 0; pp < 4; pp++) {
                    mp[pp] = mlB[pp * 32 + row];
                    lp[pp] = mlB[pp * 32 + 16 + row];
                    mt = fmaxf(mt, mp[pp]);
                }
                float fp[4];
                float lsum = 0.f;
#pragma unroll
                for (int pp = 0; pp < 4; pp++) {
                    fp[pp] = exp2a(mp[pp] - mt);
                    lsum += lp[pp] * fp[pp];
                }
                const float inv = 1.0f / lsum;
#pragma unroll
                for (int hh = 0; hh < 2; hh++) {
                    const int h = w * 2 + hh;
                    float acc = 0.f;
#pragma unroll
                    for (int pp = 0; pp < 4; pp++)
                        acc += oB[pp * 2112 + row * 132 + h * 16 + lo] * fp[pp];
                    ob[row * HD + h * 16 + lo] = acc * inv;
                }
            }
        }
        __syncthreads();   // scratch consumed before phase-2 staging
        asm volatile("s_waitcnt vmcnt(0)" ::: "memory");  // drain stores: keep counts exact
    }
#undef KSTAGE
}

extern "C" void kernel_launch(void* const* d_in, const int* in_sizes, int n_in,
                              void* d_out, int out_size, void* d_ws, size_t ws_size,
                              hipStream_t stream) {
    const float* x  = (const float*)d_in[0];
    const float* Wq = (const float*)d_in[1];
    const float* Wk = (const float*)d_in[2];
    const float* Wv = (const float*)d_in[3];

    // ws: Wt 768KB | q 4MB | k 4MB | Vt (padded) 4.06MB
    ushort* Wt = (ushort*)d_ws;
    ushort* qw = (ushort*)((char*)d_ws + 786432);
    ushort* kw = qw + (size_t)BATCH * CTX * HD;
    ushort* vw = kw + (size_t)BATCH * CTX * HD;

    wt_kernel<<<dim3(EMB / 64, HD / 64, 3), 256, 0, stream>>>(Wq, Wk, Wv, Wt);
    proj_kernel<<<dim3(512, 2), 256, 0, stream>>>(x, Wt, qw, kw, vw);
    attn_kernel<<<512, 256, 0, stream>>>(qw, kw, vw, (float*)d_out);
}

// Round 29
// 81.871 us; speedup vs baseline: 1.1458x; 1.0045x over previous
//
#include <hip/hip_runtime.h>
#include <hip/hip_bf16.h>

#define BATCH 8
#define CTX   2048
#define EMB   1024
#define HD    128
#define VSTR  2080   // Vt row stride (elems)

using bf16x8 = __attribute__((ext_vector_type(8))) short;
using fx4    = __attribute__((ext_vector_type(4))) float;

__device__ __forceinline__ ushort f2bf(float f) {
    union { float f; unsigned u; } v; v.f = f;
    unsigned u = v.u;
    u += 0x7fffu + ((u >> 16) & 1u);   // RNE
    return (ushort)(u >> 16);
}

__device__ __forceinline__ unsigned cvtpk(float a, float b) {
    unsigned r;
    asm("v_cvt_pk_bf16_f32 %0, %1, %2" : "=v"(r) : "v"(a), "v"(b));
    return r;
}

__device__ __forceinline__ float exp2a(float x) {   // v_exp_f32 = 2^x
    float r;
    asm("v_exp_f32 %0, %1" : "=v"(r) : "v"(x));
    return r;
}

__device__ __forceinline__ void gload16(const void* g, void* l) {
    __builtin_amdgcn_global_load_lds(
        (const __attribute__((address_space(1))) unsigned*)g,
        (__attribute__((address_space(3))) unsigned*)l, 16, 0, 0);
}

// ---------------- kernel 1: W (E,H) fp32 -> Wt (3,H,E) bf16 (LDS transpose) -
__global__ __launch_bounds__(256) void wt_kernel(
        const float* __restrict__ Wq, const float* __restrict__ Wk,
        const float* __restrict__ Wv, ushort* __restrict__ Wt) {
    __shared__ ushort lds[64][65];
    const int w  = blockIdx.z;
    const int e0 = blockIdx.x * 64;
    const int h0 = blockIdx.y * 64;
    const float* W = (w == 0) ? Wq : (w == 1) ? Wk : Wv;
    const int tl = threadIdx.x & 63;
    const int tg = threadIdx.x >> 6;
#pragma unroll
    for (int rr = 0; rr < 16; ++rr) {
        const int el = rr * 4 + tg;
        lds[el][tl] = f2bf(W[(size_t)(e0 + el) * HD + h0 + tl]);
    }
    __syncthreads();
#pragma unroll
    for (int rr = 0; rr < 16; ++rr) {
        const int hl = rr * 4 + tg;
        Wt[((size_t)w * HD + h0 + hl) * EMB + e0 + tl] = lds[tl][hl];
    }
}

// ---------------- kernel 2: projection v7 (split counted vmcnt) -------------
// A dbuf staged after barrier; B wave-aligned single-buffered; exact counted
// waits (FIFO: A=2 then B=6 per thread, steady-state 8 outstanding):
//   top: vmcnt(6) drains exactly A(i); mid: vmcnt(2) drains exactly B(i).
__global__ __launch_bounds__(256) void proj_kernel(
        const float* __restrict__ x, const ushort* __restrict__ Wt,
        ushort* __restrict__ q, ushort* __restrict__ k, ushort* __restrict__ vt) {
    __shared__ __align__(16) float  As[2][32 * 64];   // 16 KB (dbuf)
    __shared__ __align__(16) ushort Bs[192 * 64];     // 24 KB (single, wave-split)

    const int t    = threadIdx.x;
    const int wave = t >> 6;
    const int lane = t & 63;
    const int lo = lane & 15, hi = lane >> 4;
    const int brow = blockIdx.x * 32;
    const int bcol = blockIdx.y * 192;
    const int kph  = (blockIdx.x ^ (blockIdx.y << 3)) & 15;   // stagger

    fx4 acc[2][3];
#pragma unroll
    for (int m2 = 0; m2 < 2; m2++)
#pragma unroll
        for (int n = 0; n < 3; n++) acc[m2][n] = fx4{0.f, 0.f, 0.f, 0.f};

    const int arow_s = t >> 4;
    const int acol_s = ((t & 15) ^ (arow_s & 7)) << 2;        // f32 elems
    const char* Bw = (const char*)Bs + wave * 6144;

#define ASTAGE(bi, k0_) do {                                                    \
    _Pragma("unroll")                                                           \
    for (int r = 0; r < 2; ++r)                                                 \
        gload16(x + (size_t)(brow + r * 16 + arow_s) * EMB + (k0_) + acol_s,    \
                (char*)As[bi] + r * 4096 + wave * 1024);                        \
} while (0)

#define BSTAGE(k0_) do {                                                        \
    _Pragma("unroll")                                                           \
    for (int r = 0; r < 6; ++r) {                                               \
        const int ci  = r * 64 + lane;                                          \
        const int rowL = ci >> 3;                                               \
        const int slot = (ci & 7) ^ (rowL & 7);                                 \
        gload16(Wt + (size_t)(bcol + wave * 48 + rowL) * EMB + (k0_) + (slot << 3), \
                (char*)Bs + wave * 6144 + r * 1024);                            \
    }                                                                           \
} while (0)

    // prologue: A(0) then B(0)  (FIFO order matters for the counted waits)
    {
        const int k0 = (kph & 15) << 6;
        ASTAGE(0, k0);
        BSTAGE(k0);
    }

    for (int i = 0; i < 16; ++i) {
        // drain exactly A(i) (oldest 2 of 8); B(i) stays in flight
        asm volatile("s_waitcnt vmcnt(6)" ::: "memory");
        __builtin_amdgcn_sched_barrier(0);
        __builtin_amdgcn_s_barrier();          // A(i) visible to all waves
        __builtin_amdgcn_sched_barrier(0);

        // stage A(i+1) (its buffer's reads retired before barrier(i))
        if (i + 1 < 16) ASTAGE((i + 1) & 1, (((i + 1 + kph) & 15) << 6));

        const char* Ab = (const char*)As[i & 1];
        // ---- A fragments (both ks slices) ----
        bf16x8 afr[2][2];
#pragma unroll
        for (int m2 = 0; m2 < 2; m2++) {
            const int rowA = m2 * 16 + lo;
            const unsigned sw = (rowA & 7) << 4;
#pragma unroll
            for (int ks2 = 0; ks2 < 2; ks2++) {
                const unsigned ub = rowA * 256 + ks2 * 128 + hi * 32;
                fx4 a0 = *(const fx4*)(Ab + (ub ^ sw));
                fx4 a1 = *(const fx4*)(Ab + ((ub + 16) ^ sw));
                union { unsigned u[4]; bf16x8 v; } pk;
                pk.u[0] = cvtpk(a0[0], a0[1]);
                pk.u[1] = cvtpk(a0[2], a0[3]);
                pk.u[2] = cvtpk(a1[0], a1[1]);
                pk.u[3] = cvtpk(a1[2], a1[3]);
                afr[m2][ks2] = pk.v;
            }
        }
        // drain exactly B(i); A(i+1) (if issued) stays in flight
        if (i + 1 < 16) asm volatile("s_waitcnt vmcnt(2)" ::: "memory");
        else            asm volatile("s_waitcnt vmcnt(0)" ::: "memory");
        __builtin_amdgcn_sched_barrier(0);

        bf16x8 bfr[2][3];
#pragma unroll
        for (int ks2 = 0; ks2 < 2; ks2++)
#pragma unroll
            for (int n = 0; n < 3; n++) {
                const int rowL = n * 16 + lo;               // key = lo&7
                const unsigned ub = rowL * 128 + ks2 * 64 + hi * 16;
                bfr[ks2][n] = *(const bf16x8*)(Bw + (ub ^ ((lo & 7) << 4)));
            }
        // all ds_reads landed -> safe to overwrite this wave's B region
        asm volatile("s_waitcnt lgkmcnt(0)" ::: "memory");
        __builtin_amdgcn_sched_barrier(0);
        if (i + 1 < 16) BSTAGE((((i + 1 + kph) & 15) << 6));
        __builtin_amdgcn_sched_barrier(0);

        __builtin_amdgcn_s_setprio(1);
#pragma unroll
        for (int ks2 = 0; ks2 < 2; ks2++)
#pragma unroll
            for (int m2 = 0; m2 < 2; m2++)
#pragma unroll
                for (int n = 0; n < 3; n++)
                    acc[m2][n] = __builtin_amdgcn_mfma_f32_16x16x32_bf16(
                        afr[m2][ks2], bfr[ks2][n], acc[m2][n], 0, 0, 0);
        __builtin_amdgcn_s_setprio(0);
    }
#undef ASTAGE
#undef BSTAGE

    const float qscale = 0.045084219f;   // (1/sqrt(1024)) * log2(e)
#pragma unroll
    for (int n = 0; n < 3; n++) {
        const int col = bcol + wave * 48 + n * 16 + lo;
        const int bnn = col >> 7;
        const int cc  = col & 127;
#pragma unroll
        for (int m2 = 0; m2 < 2; m2++) {
#pragma unroll
            for (int j = 0; j < 4; j++) {
                const int r = brow + m2 * 16 + hi * 4 + j;
                if (bnn == 0)      q[(size_t)r * HD + cc] = f2bf(acc[m2][n][j] * qscale);
                else if (bnn == 1) k[(size_t)r * HD + cc] = f2bf(acc[m2][n][j]);
                else {
                    const int bb2 = r >> 11, ccc = r & (CTX - 1);
                    vt[((size_t)bb2 * HD + cc) * VSTR + ccc] = f2bf(acc[m2][n][j]);
                }
            }
        }
    }
}

// ---------------- kernel 3: attention v10c (wave-parallel merge) ------------
// 512 blocks x 4 waves, 2 blocks/CU, 2-phase serpentine (17-18 iters/block).
// Wave w owns kv cols [w*32,+32) of each 128-stripe, private K dbuf,
// barrier-free counted-vmcnt loop. Merge epilogue parallelized 4-ways:
// all waves write (o,m,l) partials to LDS; each wave merges + stores its
// own 32 output columns (h = 2w, 2w+1). oB row stride 132 f32 (bank-spread).
__global__ __launch_bounds__(256) void attn_kernel(
        const ushort* __restrict__ q, const ushort* __restrict__ k,
        const ushort* __restrict__ vt, float* __restrict__ out) {
    __shared__ __align__(16) char Ks[2][4][8192];  // [buf][wave][32 rows x 256B]
    __shared__ __align__(16) char p_lds[4][1280];  // per-wave P [16][80B]

    const int id   = blockIdx.x;
    const int b    = id & 7;                      // one batch per XCD
    const int p    = id >> 3;                     // 0..63
    const int t    = threadIdx.x;
    const int w    = t >> 6;                      // wave = kv column quarter
    const int lane = t & 63;
    const int lo = lane & 15, hi = lane >> 4;

    const ushort* qb = q  + (size_t)b * CTX * HD;
    const ushort* kb = k  + (size_t)b * CTX * HD;
    const ushort* vb = vt + (size_t)b * HD * VSTR;

    // merge scratch aliases Ks (touched only after loop + syncthreads):
    // oB [4][16][132] f32 = 33792 B; mlB [4][2][16] f32 at +33792.
    float* oB  = (float*)&Ks[0][0][0];
    float* mlB = (float*)((char*)&Ks[0][0][0] + 33792);

#define KSTAGE(bi, kv0_) do {                                                  \
    _Pragma("unroll")                                                          \
    for (int r = 0; r < 8; ++r) {                                              \
        const int rl  = r * 4 + (lane >> 4);                                   \
        const int key = (rl >> 1) & 7;                                         \
        gload16(kb + (size_t)((kv0_) + w * 32 + rl) * HD + (((lane & 15) ^ key) << 3), \
                Ks[bi][w] + r * 1024);                                         \
    }                                                                          \
} while (0)

    for (int phase = 0; phase < 2; ++phase) {
        const int qt = phase ? p : (127 - p);
        const int q0 = qt * 16;
        const int nkv = qt / 8 + 1;

        bf16x8 qf[4];
#pragma unroll
        for (int ks = 0; ks < 4; ks++)
            qf[ks] = *(const bf16x8*)(qb + (size_t)(q0 + lo) * HD + ks * 32 + hi * 8);

        fx4 o[8];
#pragma unroll
        for (int h = 0; h < 8; h++) o[h] = fx4{0.f, 0.f, 0.f, 0.f};
        float m[4], l[4];
#pragma unroll
        for (int j = 0; j < 4; j++) { m[j] = 0.f; l[j] = 0.f; }

        KSTAGE(0, 0);

        for (int it = 0; it < nkv; ++it) {
            const int kv0 = it * 128;
            // ---- V loads, global->reg (compiler guards vf before PV) ----
            bf16x8 vf[8];
#pragma unroll
            for (int h = 0; h < 8; h++)
                vf[h] = *(const bf16x8*)(vb + (size_t)(h * 16 + lo) * VSTR + kv0 + w * 32 + hi * 8);
            __builtin_amdgcn_sched_barrier(0);
            // ---- stage next K tile; counted wait for K(it) (NEVER 0) ----
            if (it + 1 < nkv) {
                KSTAGE((it + 1) & 1, kv0 + 128);
                __builtin_amdgcn_sched_barrier(0);
                asm volatile("s_waitcnt vmcnt(16)" ::: "memory");  // newer: V8+K8
            } else {
                asm volatile("s_waitcnt vmcnt(8)" ::: "memory");   // newer: V8
            }
            __builtin_amdgcn_sched_barrier(0);

            const char* Kb = Ks[it & 1][w];
            // ---- S = Q K^T; lane lo owns local kv rows (2lo, 2lo+1) ----
            fx4 s[2];
            s[0] = fx4{0.f, 0.f, 0.f, 0.f};
            s[1] = fx4{0.f, 0.f, 0.f, 0.f};
            __builtin_amdgcn_s_setprio(1);
#pragma unroll
            for (int n2 = 0; n2 < 2; n2++) {
                const int rl = 2 * lo + n2;
#pragma unroll
                for (int ks = 0; ks < 4; ks++) {
                    bf16x8 kf = *(const bf16x8*)(Kb + rl * 256 + ((ks * 64 + hi * 16) ^ ((lo & 7) << 4)));
                    s[n2] = __builtin_amdgcn_mfma_f32_16x16x32_bf16(qf[ks], kf, s[n2], 0, 0, 0);
                }
            }
            __builtin_amdgcn_s_setprio(0);

            const bool diag = (kv0 + 128 > q0);
            // ---- mask + defer-max overflow check (lane-local, exp2) ----
            float pmax[4];
            int allok = 1;
#pragma unroll
            for (int j = 0; j < 4; j++) {
                const int r = q0 + hi * 4 + j;
                if (diag) {
                    const int c0 = kv0 + w * 32 + 2 * lo;
                    if (c0 > r)     s[0][j] = -INFINITY;
                    if (c0 + 1 > r) s[1][j] = -INFINITY;
                }
                pmax[j] = fmaxf(s[0][j], s[1][j]);
                allok &= (pmax[j] <= m[j] + 23.0f);
            }
            if (!__all(allok)) {
                // slow path (rare): full cross-lane max + rescale
#pragma unroll
                for (int j = 0; j < 4; j++) {
                    float mx = pmax[j];
                    mx = fmaxf(mx, __shfl_xor(mx, 1));
                    mx = fmaxf(mx, __shfl_xor(mx, 2));
                    mx = fmaxf(mx, __shfl_xor(mx, 4));
                    mx = fmaxf(mx, __shfl_xor(mx, 8));
                    const float mn = fmaxf(m[j], mx);
                    const float f  = exp2a(m[j] - mn);
                    l[j] *= f;
#pragma unroll
                    for (int h = 0; h < 8; h++) o[h][j] *= f;
                    m[j] = mn;
                }
            }
            // ---- fast exp2 + lane-local l + packed P write ----
#pragma unroll
            for (int j = 0; j < 4; j++) {
                const float p0 = exp2a(s[0][j] - m[j]);
                const float p1 = exp2a(s[1][j] - m[j]);
                l[j] += p0 + p1;
                *(unsigned*)(p_lds[w] + (hi * 4 + j) * 80 + lo * 4) = cvtpk(p0, p1);
            }
            asm volatile("" ::: "memory");
            // ---- PV: A = P (16x32, 80B stride), B = V regs ----
            bf16x8 pa = *(const bf16x8*)(p_lds[w] + lo * 80 + hi * 16);
            __builtin_amdgcn_s_setprio(1);
#pragma unroll
            for (int h = 0; h < 8; h++)
                o[h] = __builtin_amdgcn_mfma_f32_16x16x32_bf16(pa, vf[h], o[h], 0, 0, 0);
            __builtin_amdgcn_s_setprio(0);
        }

        // ---- cross-lane l reduce (16-lane groups) ----
#pragma unroll
        for (int j = 0; j < 4; j++) {
            l[j] += __shfl_xor(l[j], 1);
            l[j] += __shfl_xor(l[j], 2);
            l[j] += __shfl_xor(l[j], 4);
            l[j] += __shfl_xor(l[j], 8);
        }

        // ---- wave-parallel merge: all waves write partials ----
        __syncthreads();   // all waves done with Ks reads
#pragma unroll
        for (int j = 0; j < 4; j++) {
            const int row = hi * 4 + j;
            if (lo == 0) { mlB[w * 32 + row] = m[j]; mlB[w * 32 + 16 + row] = l[j]; }
#pragma unroll
            for (int h = 0; h < 8; h++)
                oB[w * 2112 + row * 132 + h * 16 + lo] = o[h][j];
        }
        __syncthreads();
        // ---- each wave merges + stores its own columns h = 2w, 2w+1 ----
        {
            float* ob = out + ((size_t)b * CTX + q0) * HD;
#pragma unroll
            for (int j = 0; j < 4; j++) {
                const int row = hi * 4 + j;
                float mp[4], lp[4];
                float mt = -INFINITY;
#pragma unroll
                for (int pp = 0; pp < 4; pp++) {
                    mp[pp] = mlB[pp * 32 + row];
                    lp[pp] = mlB[pp * 32 + 16 + row];
                    mt = fmaxf(mt, mp[pp]);
                }
                float fp[4];
                float lsum = 0.f;
#pragma unroll
                for (int pp = 0; pp < 4; pp++) {
                    fp[pp] = exp2a(mp[pp] - mt);
                    lsum += lp[pp] * fp[pp];
                }
                const float inv = 1.0f / lsum;
#pragma unroll
                for (int hh = 0; hh < 2; hh++) {
                    const int h = w * 2 + hh;
                    float acc = 0.f;
#pragma unroll
                    for (int pp = 0; pp < 4; pp++)
                        acc += oB[pp * 2112 + row * 132 + h * 16 + lo] * fp[pp];
                    ob[row * HD + h * 16 + lo] = acc * inv;
                }
            }
        }
        __syncthreads();   // scratch consumed before phase-2 staging
        asm volatile("s_waitcnt vmcnt(0)" ::: "memory");  // drain stores: keep counts exact
    }
#undef KSTAGE
}

extern "C" void kernel_launch(void* const* d_in, const int* in_sizes, int n_in,
                              void* d_out, int out_size, void* d_ws, size_t ws_size,
                              hipStream_t stream) {
    const float* x  = (const float*)d_in[0];
    const float* Wq = (const float*)d_in[1];
    const float* Wk = (const float*)d_in[2];
    const float* Wv = (const float*)d_in[3];

    // ws: Wt 768KB | q 4MB | k 4MB | Vt (padded) 4.06MB
    ushort* Wt = (ushort*)d_ws;
    ushort* qw = (ushort*)((char*)d_ws + 786432);
    ushort* kw = qw + (size_t)BATCH * CTX * HD;
    ushort* vw = kw + (size_t)BATCH * CTX * HD;

    wt_kernel<<<dim3(EMB / 64, HD / 64, 3), 256, 0, stream>>>(Wq, Wk, Wv, Wt);
    proj_kernel<<<dim3(512, 2), 256, 0, stream>>>(x, Wt, qw, kw, vw);
    attn_kernel<<<512, 256, 0, stream>>>(qw, kw, vw, (float*)d_out);
}